// Round 2
// baseline (52890.546 us; speedup 1.0000x reference)
//
#include <hip/hip_runtime.h>
#include <math.h>

// ---------------------------------------------------------------------------
// CompactVidTr forward, fp32 (correctness-first baseline).
// Layout convention: token matrices are row-major [row = l*B + b][C], where
// l is the sequence position (0 = cls) and b the batch index. B=8, C=512.
//
// Workspace budget (must stay < 256 MiB):
//   X   : 3137*8 x 512  fp32   (51.4 MB)  residual stream, pooled IN PLACE
//   Ab  : 3137*8 x 512  fp32   (51.4 MB)  LN out / attention out staging
//   QKV : 3137*8 x 1536 fp32  (154.2 MB)  qkv GEMM out; reused as FFN mid
//   CLS : 8x512, IDX: 8*8*196*16 ints     (~0.8 MB)
//   total ~= 245.9 MiB
// ---------------------------------------------------------------------------

#define BB 8          // batch
#define CC 512        // channels
#define HH 8          // heads
#define HD 64         // head dim
#define WHT 196       // 14*14 spatial tokens
#define NCLS 157

// ---------------------------------------------------------------------------
__device__ __forceinline__ float wave_reduce_sum(float v) {
#pragma unroll
  for (int o = 32; o > 0; o >>= 1) v += __shfl_down(v, o, 64);
  return v;
}
__device__ __forceinline__ float wave_reduce_max(float v) {
#pragma unroll
  for (int o = 32; o > 0; o >>= 1) v = fmaxf(v, __shfl_down(v, o, 64));
  return v;
}

// ---------------------------------------------------------------------------
// Patch-embed conv: src (8,3,16,224,224), w (512,768), stride-16 16x16 patches
// ---------------------------------------------------------------------------
__global__ __launch_bounds__(256)
void conv_kernel(const float* __restrict__ src, const float* __restrict__ cw,
                 const float* __restrict__ cb, float* __restrict__ X) {
  __shared__ float patch[8][776];
  const int tid = threadIdx.x;
  const int u0 = blockIdx.x * 8;
  for (int j = 0; j < 8; j++) {
    int u = u0 + j;
    int b = u & 7;
    int s = u >> 3;
    int tt = s / WHT;
    int w2 = s % WHT;
    int ph = w2 / 14, pw = w2 % 14;
    const float* sb = src + (size_t)b * (3 * 16 * 224 * 224) +
                      (size_t)tt * (224 * 224) + (size_t)(ph * 16) * 224 + pw * 16;
    for (int e = tid; e < 768; e += 256) {
      int ci = e >> 8;
      int rem = e & 255;
      int py = rem >> 4, px = rem & 15;
      patch[j][e] = sb[(size_t)ci * (16 * 224 * 224) + py * 224 + px];
    }
  }
  __syncthreads();
  float acc0[8] = {0, 0, 0, 0, 0, 0, 0, 0};
  float acc1[8] = {0, 0, 0, 0, 0, 0, 0, 0};
  for (int e0 = 0; e0 < 768; e0 += 4) {
    float4 w0 = *(const float4*)(cw + (size_t)tid * 768 + e0);
    float4 w1 = *(const float4*)(cw + (size_t)(tid + 256) * 768 + e0);
#pragma unroll
    for (int j = 0; j < 8; j++) {
      float4 p = *(const float4*)&patch[j][e0];
      acc0[j] += w0.x * p.x + w0.y * p.y + w0.z * p.z + w0.w * p.w;
      acc1[j] += w1.x * p.x + w1.y * p.y + w1.z * p.z + w1.w * p.w;
    }
  }
  float cb0 = cb[tid], cb1 = cb[tid + 256];
  for (int j = 0; j < 8; j++) {
    int u = u0 + j;
    X[(size_t)(8 + u) * CC + tid] = acc0[j] + cb0;
    X[(size_t)(8 + u) * CC + tid + 256] = acc1[j] + cb1;
  }
}

__global__ void cls_init_kernel(const float* __restrict__ clst, float* __restrict__ X) {
  X[(size_t)blockIdx.x * CC + threadIdx.x] = clst[threadIdx.x];
}

__global__ void copy_cls_kernel(const float* __restrict__ cls, float* __restrict__ A) {
  A[(size_t)blockIdx.x * CC + threadIdx.x] = cls[(size_t)blockIdx.x * CC + threadIdx.x];
}

// ---------------------------------------------------------------------------
// LayerNorm over C=512; one block per row; optional +pos (layer0 q-input)
// ---------------------------------------------------------------------------
__global__ __launch_bounds__(256)
void ln_kernel(const float* __restrict__ X, float* __restrict__ O,
               const float* __restrict__ w, const float* __restrict__ b,
               const float* __restrict__ pos) {
  __shared__ float red[8];
  const int row = blockIdx.x, tid = threadIdx.x;
  const float* x = X + (size_t)row * CC;
  float v0 = x[tid], v1 = x[tid + 256];
  float s = wave_reduce_sum(v0 + v1);
  if ((tid & 63) == 0) red[tid >> 6] = s;
  __syncthreads();
  float mean = (red[0] + red[1] + red[2] + red[3]) * (1.f / 512.f);
  float d0 = v0 - mean, d1 = v1 - mean;
  float vs = wave_reduce_sum(d0 * d0 + d1 * d1);
  if ((tid & 63) == 0) red[4 + (tid >> 6)] = vs;
  __syncthreads();
  float var = (red[4] + red[5] + red[6] + red[7]) * (1.f / 512.f);
  float inv = 1.0f / sqrtf(var + 1e-5f);
  float o0 = d0 * inv * w[tid] + b[tid];
  float o1 = d1 * inv * w[tid + 256] + b[tid + 256];
  if (pos) {
    const float* pr = pos + (size_t)(row >> 3) * CC;
    o0 += pr[tid];
    o1 += pr[tid + 256];
  }
  O[(size_t)row * CC + tid] = o0;
  O[(size_t)row * CC + tid + 256] = o1;
}

// ---------------------------------------------------------------------------
// Generic fp32 GEMM: C = A(M,K) @ W(K,N) + bias  [+relu] [+same-row residual]
// 64x64 tile, 256 threads, 4x4 per thread, K-tiles of 16. N%64==0, K%16==0.
// ---------------------------------------------------------------------------
template <int RELU, int RES>
__global__ __launch_bounds__(256)
void gemm_kernel(const float* __restrict__ A, const float* __restrict__ W,
                 const float* __restrict__ bias, float* __restrict__ Cout,
                 int M, int N, int K, const float* __restrict__ resid) {
  __shared__ float As[16][68];
  __shared__ float Wsm[16][68];
  const int tid = threadIdx.x;
  const int tx = tid & 15, ty = tid >> 4;
  const int m0 = blockIdx.x * 64, n0 = blockIdx.y * 64;
  float acc[4][4] = {};
  for (int k0 = 0; k0 < K; k0 += 16) {
    {
      int e = tid * 4;
      int m = e >> 4, kk = e & 15;
      int gm = m0 + m;
      float4 vals;
      if (gm < M)
        vals = *(const float4*)(A + (size_t)gm * K + k0 + kk);
      else
        vals = make_float4(0.f, 0.f, 0.f, 0.f);
      As[kk + 0][m] = vals.x;
      As[kk + 1][m] = vals.y;
      As[kk + 2][m] = vals.z;
      As[kk + 3][m] = vals.w;
    }
    {
      int e = tid * 4;
      int kk = e >> 6, nn = e & 63;
      float4 vals = *(const float4*)(W + (size_t)(k0 + kk) * N + n0 + nn);
      *(float4*)&Wsm[kk][nn] = vals;
    }
    __syncthreads();
#pragma unroll
    for (int kk = 0; kk < 16; kk++) {
      float4 a4 = *(const float4*)&As[kk][ty * 4];
      float4 b4 = *(const float4*)&Wsm[kk][tx * 4];
      float av[4] = {a4.x, a4.y, a4.z, a4.w};
      float bv[4] = {b4.x, b4.y, b4.z, b4.w};
#pragma unroll
      for (int i = 0; i < 4; i++)
#pragma unroll
        for (int j = 0; j < 4; j++) acc[i][j] += av[i] * bv[j];
    }
    __syncthreads();
  }
#pragma unroll
  for (int i = 0; i < 4; i++) {
    int gm = m0 + ty * 4 + i;
    if (gm >= M) continue;
#pragma unroll
    for (int j = 0; j < 4; j++) {
      int gn = n0 + tx * 4 + j;
      float v = acc[i][j] + bias[gn];
      if (RELU) v = fmaxf(v, 0.f);
      if (RES == 1) v += resid[(size_t)gm * N + gn];
      Cout[(size_t)gm * N + gn] = v;
    }
  }
}

// ---------------------------------------------------------------------------
// Class attention: one block per (b,h); q = token0, attend over all L tokens.
// ---------------------------------------------------------------------------
__global__ __launch_bounds__(256)
void class_attn_kernel(const float* __restrict__ qkv, float* __restrict__ cls, int L) {
  __shared__ float q[64];
  __shared__ float sc[3200];
  __shared__ float red[8];
  __shared__ float pv[256];
  const int h = blockIdx.x & 7, b = blockIdx.x >> 3;
  const int tid = threadIdx.x;
  if (tid < 64) q[tid] = qkv[(size_t)b * 1536 + h * 64 + tid] * 0.125f;
  __syncthreads();
  float lmax = -3.4e38f;
  for (int l = tid; l < L; l += 256) {
    const float* kr = qkv + (size_t)(l * 8 + b) * 1536 + 512 + h * 64;
    float s = 0;
#pragma unroll
    for (int d2 = 0; d2 < 64; d2++) s += q[d2] * kr[d2];
    sc[l] = s;
    lmax = fmaxf(lmax, s);
  }
  lmax = wave_reduce_max(lmax);
  if ((tid & 63) == 0) red[tid >> 6] = lmax;
  __syncthreads();
  float gmax = fmaxf(fmaxf(red[0], red[1]), fmaxf(red[2], red[3]));
  float lsum = 0;
  for (int l = tid; l < L; l += 256) {
    float e = expf(sc[l] - gmax);
    sc[l] = e;
    lsum += e;
  }
  lsum = wave_reduce_sum(lsum);
  if ((tid & 63) == 0) red[4 + (tid >> 6)] = lsum;
  __syncthreads();
  float gsum = red[4] + red[5] + red[6] + red[7];
  const int g = tid >> 6, d = tid & 63;
  float acc = 0;
  for (int l = g; l < L; l += 4)
    acc += sc[l] * qkv[(size_t)(l * 8 + b) * 1536 + 1024 + h * 64 + d];
  pv[g * 64 + d] = acc;
  __syncthreads();
  if (g == 0) {
    float tot = pv[d] + pv[64 + d] + pv[128 + d] + pv[192 + d];
    cls[b * CC + h * 64 + d] = tot / gsum;
  }
}

// ---------------------------------------------------------------------------
// Temporal attention + sigma top-k pooling. One block per (h,b,w).
// Writes y rows: ((q*196+w)*8+b)*512 + h*64+d, and idx table for pool layers.
// ---------------------------------------------------------------------------
__global__ __launch_bounds__(256)
void temporal_attn_kernel(const float* __restrict__ qkv, float* __restrict__ Y,
                          int* __restrict__ idxbuf, int t, int tp, int pk) {
  __shared__ float qs[16 * 65], ks[16 * 65], vs[16 * 65];
  __shared__ float a[16 * 17];
  __shared__ float sig[16];
  __shared__ int keepf[16];
  __shared__ int klist[16];
  const int g = blockIdx.x;
  const int w = g % WHT;
  const int bb = (g / WHT) & 7;
  const int h = g / (WHT * 8);
  const int tid = threadIdx.x;
  const int td = t * 64;
  for (int e = tid; e < td; e += 256) {
    int tt = e >> 6, d = e & 63;
    size_t rb = (size_t)((1 + tt * WHT + w) * 8 + bb) * 1536 + h * 64 + d;
    qs[tt * 65 + d] = qkv[rb] * 0.125f;
    ks[tt * 65 + d] = qkv[rb + 512];
    vs[tt * 65 + d] = qkv[rb + 1024];
  }
  __syncthreads();
  if (tid < t * t) {
    int qi = tid / t, ki = tid % t;
    const float* qp = &qs[qi * 65];
    const float* kp = &ks[ki * 65];
    float s = 0;
#pragma unroll
    for (int d2 = 0; d2 < 64; d2++) s += qp[d2] * kp[d2];
    a[qi * 17 + ki] = s;
  }
  __syncthreads();
  if (tid < t) {
    float* row = &a[tid * 17];
    float m = row[0];
    for (int k2 = 1; k2 < t; k2++) m = fmaxf(m, row[k2]);
    float sum = 0;
    for (int k2 = 0; k2 < t; k2++) {
      float e2 = expf(row[k2] - m);
      row[k2] = e2;
      sum += e2;
    }
    float inv = 1.f / sum;
    for (int k2 = 0; k2 < t; k2++) row[k2] *= inv;
  }
  __syncthreads();
  if (pk > 0) {
    if (tid < t) {
      const float* row = &a[tid * 17];
      float mean = 0;
      for (int k2 = 0; k2 < t; k2++) mean += row[k2];
      mean /= (float)t;
      float var = 0;
      for (int k2 = 0; k2 < t; k2++) {
        float dl = row[k2] - mean;
        var += dl * dl;
      }
      var /= (float)(t - 1);
      sig[tid] = sqrtf(var);
    }
    __syncthreads();
    if (tid < t) {
      float sv = sig[tid];
      int r = 0;
      for (int q2 = 0; q2 < t; q2++) {
        float so = sig[q2];
        if (so > sv || (so == sv && q2 < tid)) r++;
      }
      keepf[tid] = (r < tp) ? 1 : 0;
    }
    __syncthreads();
    if (tid < t && keepf[tid]) {
      int ppos = 0;
      for (int q2 = 0; q2 < tid; q2++) ppos += keepf[q2];
      klist[ppos] = tid;
      idxbuf[((h * 8 + bb) * WHT + w) * 16 + ppos] = tid;
    }
  } else {
    if (tid < t) klist[tid] = tid;
  }
  __syncthreads();
  const int gq = tid >> 6, d = tid & 63;
  for (int qi = gq; qi < tp; qi += 4) {
    int qq = klist[qi];
    const float* arow = &a[qq * 17];
    float acc = 0;
    for (int k2 = 0; k2 < t; k2++) acc += arow[k2] * vs[k2 * 65 + d];
    Y[(size_t)((qi * WHT + w) * 8 + bb) * CC + h * 64 + d] = acc;
  }
}

// ---------------------------------------------------------------------------
// In-place temporal pooling of the residual stream X (reference pool_residual).
// idx is sorted ascending => klist[q] >= q => per-column ascending-q compaction
// never reads an already-overwritten row. Each column is owned by exactly one
// thread (head h = col>>6 selects which idx table), so no syncs needed.
// One block per (b,w): b = blk & 7, w = blk >> 3.
// ---------------------------------------------------------------------------
__global__ __launch_bounds__(256)
void pool_inplace_kernel(float* __restrict__ X, const int* __restrict__ idxbuf,
                         int tp) {
  const int b = blockIdx.x & 7;
  const int w = blockIdx.x >> 3;
  const int tid = threadIdx.x;
  const int c0 = tid, c1 = tid + 256;
  const int h0 = c0 >> 6, h1 = c1 >> 6;
  const int ib0 = ((h0 * 8 + b) * WHT + w) * 16;
  const int ib1 = ((h1 * 8 + b) * WHT + w) * 16;
  for (int q = 0; q < tp; q++) {
    int s0 = idxbuf[ib0 + q];
    int s1 = idxbuf[ib1 + q];
    size_t drow = (size_t)((1 + q * WHT + w) * 8 + b) * CC;
    if (s0 != q) {
      size_t srow = (size_t)((1 + s0 * WHT + w) * 8 + b) * CC;
      X[drow + c0] = X[srow + c0];
    }
    if (s1 != q) {
      size_t srow = (size_t)((1 + s1 * WHT + w) * 8 + b) * CC;
      X[drow + c1] = X[srow + c1];
    }
  }
}

// ---------------------------------------------------------------------------
// Spatial attention: one block per (h,b,tq, 16-query tile). 196 keys, d=64.
// Output written at token offset +1 (row 0 reserved for cls).
// ---------------------------------------------------------------------------
__global__ __launch_bounds__(256)
void spatial_attn_kernel(const float* __restrict__ qkv, float* __restrict__ outA, int tp) {
  __shared__ float Qs[16 * 65];
  __shared__ float Ks[32 * 65];
  __shared__ float Vs[32 * 65];
  __shared__ float S[16 * 200];
  const int g = blockIdx.x;
  const int qt = g % 13;
  const int tq = (g / 13) % tp;
  const int bb = (g / (13 * tp)) & 7;
  const int h = g / (13 * tp * 8);
  const int tid = threadIdx.x;
#pragma unroll
  for (int r = 0; r < 4; r++) {
    int e = tid + r * 256;
    int i = e >> 6, d = e & 63;
    int wq = qt * 16 + i;
    float v = 0.f;
    if (wq < WHT) v = qkv[(size_t)((tq * WHT + wq) * 8 + bb) * 1536 + h * 64 + d] * 0.125f;
    Qs[i * 65 + d] = v;
  }
  __syncthreads();
  for (int kc = 0; kc < WHT; kc += 32) {
    int cn = min(32, WHT - kc);
#pragma unroll
    for (int r = 0; r < 8; r++) {
      int e = tid + r * 256;
      int j = e >> 6, d = e & 63;
      if (j < cn)
        Ks[j * 65 + d] = qkv[(size_t)((tq * WHT + kc + j) * 8 + bb) * 1536 + 512 + h * 64 + d];
    }
    __syncthreads();
    for (int p = tid; p < 16 * cn; p += 256) {
      int i = p / cn, j = p % cn;
      const float* qp = &Qs[i * 65];
      const float* kp = &Ks[j * 65];
      float s = 0;
#pragma unroll
      for (int d2 = 0; d2 < 64; d2++) s += qp[d2] * kp[d2];
      S[i * 200 + kc + j] = s;
    }
    __syncthreads();
  }
  if (tid < 16) {
    float* row = &S[tid * 200];
    float m = row[0];
    for (int j = 1; j < WHT; j++) m = fmaxf(m, row[j]);
    float sum = 0;
    for (int j = 0; j < WHT; j++) {
      float e2 = expf(row[j] - m);
      row[j] = e2;
      sum += e2;
    }
    float inv = 1.f / sum;
    for (int j = 0; j < WHT; j++) row[j] *= inv;
  }
  __syncthreads();
  const int gq = tid >> 6, d = tid & 63;
  float acc[4] = {0, 0, 0, 0};
  for (int vc = 0; vc < WHT; vc += 32) {
    int cn = min(32, WHT - vc);
#pragma unroll
    for (int r = 0; r < 8; r++) {
      int e = tid + r * 256;
      int j = e >> 6, dd = e & 63;
      if (j < cn)
        Vs[j * 65 + dd] = qkv[(size_t)((tq * WHT + vc + j) * 8 + bb) * 1536 + 1024 + h * 64 + dd];
    }
    __syncthreads();
#pragma unroll
    for (int m2 = 0; m2 < 4; m2++) {
      int i = gq + m2 * 4;
      const float* arow = &S[i * 200 + vc];
      float av = acc[m2];
      for (int j = 0; j < cn; j++) av += arow[j] * Vs[j * 65 + d];
      acc[m2] = av;
    }
    __syncthreads();
  }
#pragma unroll
  for (int m2 = 0; m2 < 4; m2++) {
    int i = gq + m2 * 4;
    int wq = qt * 16 + i;
    if (wq < WHT)
      outA[(size_t)((1 + tq * WHT + wq) * 8 + bb) * CC + h * 64 + d] = acc[m2];
  }
}

// ---------------------------------------------------------------------------
// Final LN (token 0 only) + classifier head
// ---------------------------------------------------------------------------
__global__ __launch_bounds__(256)
void head_kernel(const float* __restrict__ X, const float* __restrict__ enw,
                 const float* __restrict__ enb, const float* __restrict__ fcw,
                 const float* __restrict__ fcb, float* __restrict__ out) {
  __shared__ float nx[512];
  __shared__ float red[8];
  const int b = blockIdx.x, tid = threadIdx.x;
  const float* x = X + (size_t)b * CC;
  float v0 = x[tid], v1 = x[tid + 256];
  float s = wave_reduce_sum(v0 + v1);
  if ((tid & 63) == 0) red[tid >> 6] = s;
  __syncthreads();
  float mean = (red[0] + red[1] + red[2] + red[3]) * (1.f / 512.f);
  float d0 = v0 - mean, d1 = v1 - mean;
  float vs = wave_reduce_sum(d0 * d0 + d1 * d1);
  if ((tid & 63) == 0) red[4 + (tid >> 6)] = vs;
  __syncthreads();
  float var = (red[4] + red[5] + red[6] + red[7]) * (1.f / 512.f);
  float inv = 1.0f / sqrtf(var + 1e-5f);
  nx[tid] = d0 * inv * enw[tid] + enb[tid];
  nx[tid + 256] = d1 * inv * enw[tid + 256] + enb[tid + 256];
  __syncthreads();
  if (tid < NCLS) {
    float acc = fcb[tid];
    for (int c = 0; c < 512; c++) acc += nx[c] * fcw[c * NCLS + tid];
    out[b * NCLS + tid] = acc;
  }
}

// ---------------------------------------------------------------------------
extern "C" void kernel_launch(void* const* d_in, const int* in_sizes, int n_in,
                              void* d_out, int out_size, void* d_ws, size_t ws_size,
                              hipStream_t stream) {
  (void)in_sizes; (void)n_in; (void)out_size; (void)ws_size;
  const float* src  = (const float*)d_in[0];
  const float* cw   = (const float*)d_in[1];
  const float* cb   = (const float*)d_in[2];
  const float* clst = (const float*)d_in[3];
  const float* pos  = (const float*)d_in[4];
  const float* Wt   = (const float*)d_in[5];
  const float* bt   = (const float*)d_in[6];
  const float* Wsp  = (const float*)d_in[7];
  const float* bsp  = (const float*)d_in[8];
  const float* Wo   = (const float*)d_in[9];
  const float* bo   = (const float*)d_in[10];
  const float* n1w  = (const float*)d_in[11];
  const float* n1b  = (const float*)d_in[12];
  const float* n2w  = (const float*)d_in[13];
  const float* n2b  = (const float*)d_in[14];
  const float* W1   = (const float*)d_in[15];
  const float* b1   = (const float*)d_in[16];
  const float* W2   = (const float*)d_in[17];
  const float* b2   = (const float*)d_in[18];
  const float* enw  = (const float*)d_in[19];
  const float* enb  = (const float*)d_in[20];
  const float* fcw  = (const float*)d_in[21];
  const float* fcb  = (const float*)d_in[22];

  float* ws = (float*)d_ws;
  const size_t TOKR = (size_t)3137 * 8;
  float* X0  = ws;                        // TOKR*512
  float* Ab  = X0 + TOKR * 512;           // TOKR*512
  float* QKV = Ab + TOKR * 512;           // TOKR*1536 (also FFN-mid chunks)
  float* CLS = QKV + TOKR * 1536;         // 8*512
  int*   IDX = (int*)(CLS + 8 * 512);     // 8*8*196*16 ints

  conv_kernel<<<3136, 256, 0, stream>>>(src, cw, cb, X0);
  cls_init_kernel<<<8, 512, 0, stream>>>(clst, X0);

  float* Xc = X0;
  int t = 16;
  const int FFN_CHUNK = 16384;  // rows; mid = 16384*2048 floats <= TOKR*1536
  for (int i = 0; i < 6; i++) {
    const int pk = (i & 1) ? 2 : 0;  // layers 1,3,5 pool 2 tokens each
    const int tp = t - pk;
    const int L = 1 + t * WHT;
    const int Lo = 1 + tp * WHT;
    const int M = L * 8, Mo = Lo * 8, My = tp * WHT * 8;

    ln_kernel<<<M, 256, 0, stream>>>(Xc, Ab, n1w + (size_t)i * 512, n1b + (size_t)i * 512,
                                     (i == 0) ? pos : nullptr);
    gemm_kernel<0, 0><<<dim3((M + 63) / 64, 24), 256, 0, stream>>>(
        Ab, Wt + (size_t)i * 512 * 1536, bt + (size_t)i * 1536, QKV, M, 1536, 512,
        nullptr);
    class_attn_kernel<<<64, 256, 0, stream>>>(QKV, CLS, L);
    temporal_attn_kernel<<<HH * BB * WHT, 256, 0, stream>>>(QKV, Ab, IDX, t, tp, pk);
    gemm_kernel<0, 0><<<dim3((My + 63) / 64, 24), 256, 0, stream>>>(
        Ab, Wsp + (size_t)i * 512 * 1536, bsp + (size_t)i * 1536, QKV, My, 1536, 512,
        nullptr);
    copy_cls_kernel<<<8, 512, 0, stream>>>(CLS, Ab);
    spatial_attn_kernel<<<HH * BB * tp * 13, 256, 0, stream>>>(QKV, Ab, tp);
    if (pk > 0)
      pool_inplace_kernel<<<8 * WHT, 256, 0, stream>>>(Xc, IDX, tp);
    gemm_kernel<0, 1><<<dim3((Mo + 63) / 64, 8), 256, 0, stream>>>(
        Ab, Wo + (size_t)i * 512 * 512, bo + (size_t)i * 512, Xc, Mo, 512, 512, Xc);
    ln_kernel<<<Mo, 256, 0, stream>>>(Xc, Ab, n2w + (size_t)i * 512, n2b + (size_t)i * 512,
                                      nullptr);
    for (int off = 0; off < Mo; off += FFN_CHUNK) {
      int R = Mo - off;
      if (R > FFN_CHUNK) R = FFN_CHUNK;
      gemm_kernel<1, 0><<<dim3((R + 63) / 64, 32), 256, 0, stream>>>(
          Ab + (size_t)off * 512, W1 + (size_t)i * 512 * 2048, b1 + (size_t)i * 2048,
          QKV, R, 2048, 512, nullptr);
      gemm_kernel<0, 1><<<dim3((R + 63) / 64, 8), 256, 0, stream>>>(
          QKV, W2 + (size_t)i * 2048 * 512, b2 + (size_t)i * 512,
          Xc + (size_t)off * 512, R, 512, 2048, Xc + (size_t)off * 512);
    }
    t = tp;
  }
  head_kernel<<<8, 256, 0, stream>>>(Xc, enw, enb, fcw, fcb, (float*)d_out);
}